// Round 2
// baseline (156.491 us; speedup 1.0000x reference)
//
#include <hip/hip_runtime.h>
#include <hip/hip_bf16.h>

typedef short short8 __attribute__((ext_vector_type(8)));
typedef float f32x4  __attribute__((ext_vector_type(4)));

#define ND 128
#define LD 128
#define EE 128
#define NQ 128
#define LQ 32
#define LDS_STRIDE 136   // 128 + 8 bf16 pad: breaks 256B power-of-2 stride

// ---- Kernel 1: fp32 -> bf16 convert; query transposed [Nq,E,Lq] -> [Nq,Lq,E] ----
__global__ __launch_bounds__(256)
void convert_kernel(const float* __restrict__ doc, const float* __restrict__ qry,
                    __hip_bfloat16* __restrict__ docB, __hip_bfloat16* __restrict__ qB) {
  const int DOC4 = (ND * LD * EE) / 4;   // 524288 float4 chunks
  int gid = blockIdx.x * 256 + threadIdx.x;
  if (gid < DOC4) {
    float4 v = reinterpret_cast<const float4*>(doc)[gid];
    union { ushort4 u; __hip_bfloat16 b[4]; } o;
    o.b[0] = __float2bfloat16(v.x);
    o.b[1] = __float2bfloat16(v.y);
    o.b[2] = __float2bfloat16(v.z);
    o.b[3] = __float2bfloat16(v.w);
    reinterpret_cast<ushort4*>(docB)[gid] = o.u;
  } else {
    int t = gid - DOC4;              // flat index into qB [NQ][LQ][EE]
    int q = t >> 12;                 // / (LQ*EE) = 4096
    int rem = t & 4095;
    int l = rem >> 7;                // / EE
    int e = rem & 127;
    qB[t] = __float2bfloat16(qry[(q << 12) + (e << 5) + l]);  // qry[q][e][l]
  }
}

// ---- Kernel 2: fused maxsim. Block = (doc d, 16 queries). Grid 128x8 = 1024 blocks
// = exactly 4 blocks/CU, ALL co-resident (LDS 34816*4 = 136KB <= 160KB; VGPR <= 128).
// One wave = 4 queries, processed as 2 sequential pairs (B-frags 64 VGPRs/pair). ----
__global__ __launch_bounds__(256, 4)
void maxsim_kernel(const __hip_bfloat16* __restrict__ docB,
                   const __hip_bfloat16* __restrict__ qB,
                   float* __restrict__ out) {
  __shared__ __hip_bfloat16 sdoc[LD * LDS_STRIDE];
  const int d    = blockIdx.x;
  const int qblk = blockIdx.y;
  const int tid  = threadIdx.x;

  // Stage doc[d] (128x128 bf16 = 32KB) into LDS, padded row stride. 16B per lane.
  {
    const uint4* src = reinterpret_cast<const uint4*>(docB + d * (LD * EE));
    #pragma unroll
    for (int it = 0; it < 8; ++it) {
      int idx = it * 256 + tid;      // chunk of 8 bf16; 16 chunks per row
      int row = idx >> 4;
      int c8  = (idx & 15) << 3;
      *reinterpret_cast<uint4*>(&sdoc[row * LDS_STRIDE + c8]) = src[idx];
    }
  }
  __syncthreads();

  const int wave = tid >> 6;
  const int lane = tid & 63;
  const int ln15 = lane & 15;        // m (A) / n (B) index within 16-tile
  const int quad = lane >> 4;        // k-group: k = quad*8 + j

  #pragma unroll 1
  for (int p = 0; p < 2; ++p) {
    const int q0 = qblk * 16 + wave * 4 + p * 2;

    // B fragments for 2 queries, 2 n-tiles (Lq=32), 4 k-steps — in registers.
    short8 bfrag[2][2][4];
    #pragma unroll
    for (int qq = 0; qq < 2; ++qq) {
      const __hip_bfloat16* qp = qB + (q0 + qq) * (LQ * EE);
      #pragma unroll
      for (int nt = 0; nt < 2; ++nt)
        #pragma unroll
        for (int ks = 0; ks < 4; ++ks)
          bfrag[qq][nt][ks] = *reinterpret_cast<const short8*>(
              qp + (nt * 16 + ln15) * EE + ks * 32 + quad * 8);
    }

    f32x4 colmax[2][2];
    #pragma unroll
    for (int qq = 0; qq < 2; ++qq)
      #pragma unroll
      for (int nt = 0; nt < 2; ++nt)
        colmax[qq][nt] = (f32x4){-3.0e38f, -3.0e38f, -3.0e38f, -3.0e38f};

    // M loop: 8 tiles of 16 doc tokens. Fresh acc per tile -> fold into col-max.
    #pragma unroll
    for (int mt = 0; mt < 8; ++mt) {
      f32x4 acc[2][2];
      #pragma unroll
      for (int qq = 0; qq < 2; ++qq)
        #pragma unroll
        for (int nt = 0; nt < 2; ++nt)
          acc[qq][nt] = (f32x4){0.f, 0.f, 0.f, 0.f};

      #pragma unroll
      for (int ks = 0; ks < 4; ++ks) {
        short8 a = *reinterpret_cast<const short8*>(
            &sdoc[(mt * 16 + ln15) * LDS_STRIDE + ks * 32 + quad * 8]);
        acc[0][0] = __builtin_amdgcn_mfma_f32_16x16x32_bf16(a, bfrag[0][0][ks], acc[0][0], 0, 0, 0);
        acc[0][1] = __builtin_amdgcn_mfma_f32_16x16x32_bf16(a, bfrag[0][1][ks], acc[0][1], 0, 0, 0);
        acc[1][0] = __builtin_amdgcn_mfma_f32_16x16x32_bf16(a, bfrag[1][0][ks], acc[1][0], 0, 0, 0);
        acc[1][1] = __builtin_amdgcn_mfma_f32_16x16x32_bf16(a, bfrag[1][1][ks], acc[1][1], 0, 0, 0);
      }

      #pragma unroll
      for (int qq = 0; qq < 2; ++qq)
        #pragma unroll
        for (int nt = 0; nt < 2; ++nt)
          #pragma unroll
          for (int r = 0; r < 4; ++r)
            colmax[qq][nt][r] = fmaxf(colmax[qq][nt][r], acc[qq][nt][r]);
    }

    // Epilogue: C/D layout col=lane&15, row=quad*4+reg. Max over rows, sum 32 cols.
    #pragma unroll
    for (int qq = 0; qq < 2; ++qq) {
      float m0 = fmaxf(fmaxf(colmax[qq][0][0], colmax[qq][0][1]),
                       fmaxf(colmax[qq][0][2], colmax[qq][0][3]));
      float m1 = fmaxf(fmaxf(colmax[qq][1][0], colmax[qq][1][1]),
                       fmaxf(colmax[qq][1][2], colmax[qq][1][3]));
      m0 = fmaxf(m0, __shfl_xor(m0, 16, 64));
      m0 = fmaxf(m0, __shfl_xor(m0, 32, 64));
      m1 = fmaxf(m1, __shfl_xor(m1, 16, 64));
      m1 = fmaxf(m1, __shfl_xor(m1, 32, 64));
      float s = m0 + m1;                       // cols (lane&15) and (lane&15)+16
      s += __shfl_xor(s, 1, 64);
      s += __shfl_xor(s, 2, 64);
      s += __shfl_xor(s, 4, 64);
      s += __shfl_xor(s, 8, 64);
      if (lane == 0) out[(q0 + qq) * ND + d] = s;
    }
  }
}

extern "C" void kernel_launch(void* const* d_in, const int* in_sizes, int n_in,
                              void* d_out, int out_size, void* d_ws, size_t ws_size,
                              hipStream_t stream) {
  const float* doc = (const float*)d_in[0];   // [128,128,128] fp32
  const float* qry = (const float*)d_in[1];   // [128,128,32]  fp32
  float* out = (float*)d_out;                 // [128,128]     fp32

  __hip_bfloat16* docB = (__hip_bfloat16*)d_ws;            // 4 MiB
  __hip_bfloat16* qB   = docB + ND * LD * EE;              // 1 MiB

  convert_kernel<<<dim3(4096), dim3(256), 0, stream>>>(doc, qry, docB, qB);
  maxsim_kernel<<<dim3(ND, NQ / 16), dim3(256), 0, stream>>>(docB, qB, out);
}

// Round 3
// 90.287 us; speedup vs baseline: 1.7333x; 1.7333x over previous
//
#include <hip/hip_runtime.h>
#include <hip/hip_bf16.h>

typedef short short8 __attribute__((ext_vector_type(8)));
typedef float f32x4  __attribute__((ext_vector_type(4)));

#define ND 128
#define LD 128
#define EE 128
#define NQ 128
#define LQ 32
#define LDS_STRIDE 136   // 128 + 8 bf16 pad: breaks 256B power-of-2 stride

// ---- Kernel 1: query fp32 [E][Lq] -> bf16 [Lq][E], coalesced via LDS transpose ----
__global__ __launch_bounds__(256)
void qconvert_kernel(const float* __restrict__ qry, __hip_bfloat16* __restrict__ qB) {
  __shared__ float s[LQ][EE + 1];     // 32 x 129 fp32, pad breaks bank stride
  const int q   = blockIdx.x;
  const int tid = threadIdx.x;
  const float* src = qry + q * (EE * LQ);
  // coalesced float4 read of [E][L] (1024 chunks), scatter into LDS [l][e]
  #pragma unroll
  for (int i = 0; i < 4; ++i) {
    int c = i * 256 + tid;
    int e = c >> 3;                   // 8 chunks (32 floats = one e-row) per e
    int l = (c & 7) << 2;
    float4 v = reinterpret_cast<const float4*>(src)[c];
    s[l + 0][e] = v.x;
    s[l + 1][e] = v.y;
    s[l + 2][e] = v.z;
    s[l + 3][e] = v.w;
  }
  __syncthreads();
  // coalesced ushort4 write of [L][E] bf16 (1024 chunks)
  __hip_bfloat16* dst = qB + q * (LQ * EE);
  #pragma unroll
  for (int i = 0; i < 4; ++i) {
    int c = i * 256 + tid;
    int l = c >> 5;                   // 32 chunks (128 e) per l-row
    int e = (c & 31) << 2;
    union { ushort4 u; __hip_bfloat16 b[4]; } o;
    o.b[0] = __float2bfloat16(s[l][e + 0]);
    o.b[1] = __float2bfloat16(s[l][e + 1]);
    o.b[2] = __float2bfloat16(s[l][e + 2]);
    o.b[3] = __float2bfloat16(s[l][e + 3]);
    reinterpret_cast<ushort4*>(dst)[c] = o.u;
  }
}

// ---- Kernel 2: fused maxsim. Block = (doc d, 16 queries), grid 128x8 = 1024.
// Doc fp32 is converted to bf16 in-register during LDS staging (no docB pass).
// One wave = 4 queries as 2 sequential passes of 2 (bfrag 64 VGPRs per pass).
// No min-waves launch bound: let the allocator use ~105 regs WITHOUT spilling
// (R1/R2 post-mortem: forcing 128-reg budget spilled bfrag -> 200MB scratch). ----
__global__ __launch_bounds__(256)
void maxsim_kernel(const float* __restrict__ doc,
                   const __hip_bfloat16* __restrict__ qB,
                   float* __restrict__ out) {
  __shared__ __hip_bfloat16 sdoc[LD * LDS_STRIDE];
  const int d    = blockIdx.x;
  const int qblk = blockIdx.y;
  const int tid  = threadIdx.x;

  // Stage doc[d] (128x128): read fp32 float4 coalesced, convert, write bf16 LDS.
  {
    const float4* src = reinterpret_cast<const float4*>(doc + d * (LD * EE));
    #pragma unroll
    for (int it = 0; it < 16; ++it) {
      int c = it * 256 + tid;         // float4 chunk; 32 chunks per row
      int row = c >> 5;
      int col = (c & 31) << 2;
      float4 v = src[c];
      union { ushort4 u; __hip_bfloat16 b[4]; } o;
      o.b[0] = __float2bfloat16(v.x);
      o.b[1] = __float2bfloat16(v.y);
      o.b[2] = __float2bfloat16(v.z);
      o.b[3] = __float2bfloat16(v.w);
      *reinterpret_cast<ushort4*>(&sdoc[row * LDS_STRIDE + col]) = o.u;
    }
  }
  __syncthreads();

  const int wave = tid >> 6;
  const int lane = tid & 63;
  const int ln15 = lane & 15;        // m (A) / n (B) index within 16-tile
  const int quad = lane >> 4;        // k-group: k = quad*8 + j

  #pragma unroll 1
  for (int p = 0; p < 2; ++p) {
    const int q0 = qblk * 16 + wave * 4 + p * 2;

    // B fragments: 2 queries x 2 n-tiles x 4 k-steps, in registers (64 VGPRs).
    short8 bfrag[2][2][4];
    #pragma unroll
    for (int qq = 0; qq < 2; ++qq) {
      const __hip_bfloat16* qp = qB + (q0 + qq) * (LQ * EE);
      #pragma unroll
      for (int nt = 0; nt < 2; ++nt)
        #pragma unroll
        for (int ks = 0; ks < 4; ++ks)
          bfrag[qq][nt][ks] = *reinterpret_cast<const short8*>(
              qp + (nt * 16 + ln15) * EE + ks * 32 + quad * 8);
    }

    // Scalar running max per (query, n-tile): rows folded immediately each mt.
    float colmax[2][2] = {{-3.0e38f, -3.0e38f}, {-3.0e38f, -3.0e38f}};

    #pragma unroll
    for (int mt = 0; mt < 8; ++mt) {
      f32x4 acc[2][2];
      #pragma unroll
      for (int qq = 0; qq < 2; ++qq)
        #pragma unroll
        for (int nt = 0; nt < 2; ++nt)
          acc[qq][nt] = (f32x4){0.f, 0.f, 0.f, 0.f};

      #pragma unroll
      for (int ks = 0; ks < 4; ++ks) {
        short8 a = *reinterpret_cast<const short8*>(
            &sdoc[(mt * 16 + ln15) * LDS_STRIDE + ks * 32 + quad * 8]);
        acc[0][0] = __builtin_amdgcn_mfma_f32_16x16x32_bf16(a, bfrag[0][0][ks], acc[0][0], 0, 0, 0);
        acc[0][1] = __builtin_amdgcn_mfma_f32_16x16x32_bf16(a, bfrag[0][1][ks], acc[0][1], 0, 0, 0);
        acc[1][0] = __builtin_amdgcn_mfma_f32_16x16x32_bf16(a, bfrag[1][0][ks], acc[1][0], 0, 0, 0);
        acc[1][1] = __builtin_amdgcn_mfma_f32_16x16x32_bf16(a, bfrag[1][1][ks], acc[1][1], 0, 0, 0);
      }

      // Fold this tile's 4 doc-token rows into the scalar running max.
      #pragma unroll
      for (int qq = 0; qq < 2; ++qq)
        #pragma unroll
        for (int nt = 0; nt < 2; ++nt)
          colmax[qq][nt] = fmaxf(colmax[qq][nt],
                                 fmaxf(fmaxf(acc[qq][nt][0], acc[qq][nt][1]),
                                       fmaxf(acc[qq][nt][2], acc[qq][nt][3])));
    }

    // Epilogue: C/D layout col=lane&15, row=quad*4+reg. Max over row-groups
    // (shfl 16/32), then sum over 32 columns (two tiles + shfl 1/2/4/8).
    #pragma unroll
    for (int qq = 0; qq < 2; ++qq) {
      float m0 = colmax[qq][0];
      float m1 = colmax[qq][1];
      m0 = fmaxf(m0, __shfl_xor(m0, 16, 64));
      m0 = fmaxf(m0, __shfl_xor(m0, 32, 64));
      m1 = fmaxf(m1, __shfl_xor(m1, 16, 64));
      m1 = fmaxf(m1, __shfl_xor(m1, 32, 64));
      float s = m0 + m1;                       // cols (lane&15) and (lane&15)+16
      s += __shfl_xor(s, 1, 64);
      s += __shfl_xor(s, 2, 64);
      s += __shfl_xor(s, 4, 64);
      s += __shfl_xor(s, 8, 64);
      if (lane == 0) out[(q0 + qq) * ND + d] = s;
    }
  }
}

extern "C" void kernel_launch(void* const* d_in, const int* in_sizes, int n_in,
                              void* d_out, int out_size, void* d_ws, size_t ws_size,
                              hipStream_t stream) {
  const float* doc = (const float*)d_in[0];   // [128,128,128] fp32
  const float* qry = (const float*)d_in[1];   // [128,128,32]  fp32
  float* out = (float*)d_out;                 // [128,128]     fp32

  __hip_bfloat16* qB = (__hip_bfloat16*)d_ws; // 1 MiB: query bf16 [Nq][Lq][E]

  qconvert_kernel<<<dim3(NQ), dim3(256), 0, stream>>>(qry, qB);
  maxsim_kernel<<<dim3(ND, NQ / 16), dim3(256), 0, stream>>>(doc, qB, out);
}

// Round 4
// 82.485 us; speedup vs baseline: 1.8972x; 1.0946x over previous
//
#include <hip/hip_runtime.h>
#include <hip/hip_bf16.h>

typedef short short8 __attribute__((ext_vector_type(8)));
typedef float f32x4  __attribute__((ext_vector_type(4)));

#define ND 128
#define LD 128
#define EE 128
#define NQ 128
#define LQ 32
#define LDS_STRIDE 136   // 128 + 8 bf16 pad: breaks 256B power-of-2 stride
#define GDOCS 2          // docs per block; grid = (ND/GDOCS, NQ/8) = 64x16 = 1024 = 4/CU

// ---- Kernel 1: merged convert.
// blocks [0, 2048): doc fp32 -> bf16, straight copy-cast (1 float4/thread)
// blocks [2048, 2176): query fp32 [E][Lq] -> bf16 [Lq][E] via LDS transpose ----
__global__ __launch_bounds__(256)
void convert_kernel(const float* __restrict__ doc, const float* __restrict__ qry,
                    __hip_bfloat16* __restrict__ docB, __hip_bfloat16* __restrict__ qB) {
  const int tid = threadIdx.x;
  if (blockIdx.x < 2048) {
    int gid = blockIdx.x * 256 + tid;        // 524288 float4 chunks of doc
    float4 v = reinterpret_cast<const float4*>(doc)[gid];
    union { ushort4 u; __hip_bfloat16 b[4]; } o;
    o.b[0] = __float2bfloat16(v.x);
    o.b[1] = __float2bfloat16(v.y);
    o.b[2] = __float2bfloat16(v.z);
    o.b[3] = __float2bfloat16(v.w);
    reinterpret_cast<ushort4*>(docB)[gid] = o.u;
    return;
  }
  __shared__ float s[LQ][EE + 1];            // 32 x 129 fp32
  const int q = blockIdx.x - 2048;
  const float* src = qry + q * (EE * LQ);
  #pragma unroll
  for (int i = 0; i < 4; ++i) {              // coalesced float4 read of [E][L]
    int c = i * 256 + tid;
    int e = c >> 3;
    int l = (c & 7) << 2;
    float4 v = reinterpret_cast<const float4*>(src)[c];
    s[l + 0][e] = v.x;
    s[l + 1][e] = v.y;
    s[l + 2][e] = v.z;
    s[l + 3][e] = v.w;
  }
  __syncthreads();
  __hip_bfloat16* dst = qB + q * (LQ * EE);
  #pragma unroll
  for (int i = 0; i < 4; ++i) {              // coalesced ushort4 write of [L][E]
    int c = i * 256 + tid;
    int l = c >> 5;
    int e = (c & 31) << 2;
    union { ushort4 u; __hip_bfloat16 b[4]; } o;
    o.b[0] = __float2bfloat16(s[l][e + 0]);
    o.b[1] = __float2bfloat16(s[l][e + 1]);
    o.b[2] = __float2bfloat16(s[l][e + 2]);
    o.b[3] = __float2bfloat16(s[l][e + 3]);
    reinterpret_cast<ushort4*>(dst)[c] = o.u;
  }
}

// ---- Kernel 2: fused maxsim, query-resident. Block = (GDOCS docs, 8 queries).
// Wave holds its 2 queries' B-frags (64 VGPRs) for the WHOLE kernel; loops over
// docs staged one at a time in LDS. No per-pass bfrag reload, doc staged
// NQ/8 = 16x total (bf16, halved bytes). No min-waves bound (R2: forcing the
// 128-reg budget spilled bfrag -> 200MB scratch traffic). ----
__global__ __launch_bounds__(256)
void maxsim_kernel(const __hip_bfloat16* __restrict__ docB,
                   const __hip_bfloat16* __restrict__ qB,
                   float* __restrict__ out) {
  __shared__ __hip_bfloat16 sdoc[LD * LDS_STRIDE];
  const int d0   = blockIdx.x * GDOCS;
  const int qblk = blockIdx.y;
  const int tid  = threadIdx.x;
  const int wave = tid >> 6;
  const int lane = tid & 63;
  const int ln15 = lane & 15;        // m (A) / n (B) index within 16-tile
  const int quad = lane >> 4;        // k-group: k = quad*8 + j
  const int q0   = qblk * 8 + wave * 2;

  // B fragments: 2 queries x 2 n-tiles x 4 k-steps — loaded ONCE, held in regs.
  short8 bfrag[2][2][4];
  #pragma unroll
  for (int qq = 0; qq < 2; ++qq) {
    const __hip_bfloat16* qp = qB + (q0 + qq) * (LQ * EE);
    #pragma unroll
    for (int nt = 0; nt < 2; ++nt)
      #pragma unroll
      for (int ks = 0; ks < 4; ++ks)
        bfrag[qq][nt][ks] = *reinterpret_cast<const short8*>(
            qp + (nt * 16 + ln15) * EE + ks * 32 + quad * 8);
  }

  #pragma unroll 1
  for (int g = 0; g < GDOCS; ++g) {
    const int d = d0 + g;
    __syncthreads();   // g>0: don't overwrite sdoc while others still read it
    // Stage docB[d] (32KB bf16) into padded LDS: 2048 uint4 chunks, 8/thread.
    {
      const uint4* src = reinterpret_cast<const uint4*>(docB + d * (LD * EE));
      #pragma unroll
      for (int it = 0; it < 8; ++it) {
        int idx = it * 256 + tid;    // 16 chunks (of 8 bf16) per row
        int row = idx >> 4;
        int c8  = (idx & 15) << 3;
        *reinterpret_cast<uint4*>(&sdoc[row * LDS_STRIDE + c8]) =  src[idx];
      }
    }
    __syncthreads();

    // Scalar running max per (query, n-tile).
    float colmax[2][2] = {{-3.0e38f, -3.0e38f}, {-3.0e38f, -3.0e38f}};

    #pragma unroll
    for (int mt = 0; mt < 8; ++mt) {
      f32x4 acc[2][2];
      #pragma unroll
      for (int qq = 0; qq < 2; ++qq)
        #pragma unroll
        for (int nt = 0; nt < 2; ++nt)
          acc[qq][nt] = (f32x4){0.f, 0.f, 0.f, 0.f};

      #pragma unroll
      for (int ks = 0; ks < 4; ++ks) {
        short8 a = *reinterpret_cast<const short8*>(
            &sdoc[(mt * 16 + ln15) * LDS_STRIDE + ks * 32 + quad * 8]);
        acc[0][0] = __builtin_amdgcn_mfma_f32_16x16x32_bf16(a, bfrag[0][0][ks], acc[0][0], 0, 0, 0);
        acc[0][1] = __builtin_amdgcn_mfma_f32_16x16x32_bf16(a, bfrag[0][1][ks], acc[0][1], 0, 0, 0);
        acc[1][0] = __builtin_amdgcn_mfma_f32_16x16x32_bf16(a, bfrag[1][0][ks], acc[1][0], 0, 0, 0);
        acc[1][1] = __builtin_amdgcn_mfma_f32_16x16x32_bf16(a, bfrag[1][1][ks], acc[1][1], 0, 0, 0);
      }

      // Fold this tile's 4 doc-token rows into the scalar running max.
      #pragma unroll
      for (int qq = 0; qq < 2; ++qq)
        #pragma unroll
        for (int nt = 0; nt < 2; ++nt)
          colmax[qq][nt] = fmaxf(colmax[qq][nt],
                                 fmaxf(fmaxf(acc[qq][nt][0], acc[qq][nt][1]),
                                       fmaxf(acc[qq][nt][2], acc[qq][nt][3])));
    }

    // Epilogue: C/D layout col=lane&15, row=quad*4+reg. Max over row-groups
    // (shfl 16/32), sum over 32 cols (two tiles + shfl 1/2/4/8).
    #pragma unroll
    for (int qq = 0; qq < 2; ++qq) {
      float m0 = colmax[qq][0];
      float m1 = colmax[qq][1];
      m0 = fmaxf(m0, __shfl_xor(m0, 16, 64));
      m0 = fmaxf(m0, __shfl_xor(m0, 32, 64));
      m1 = fmaxf(m1, __shfl_xor(m1, 16, 64));
      m1 = fmaxf(m1, __shfl_xor(m1, 32, 64));
      float s = m0 + m1;
      s += __shfl_xor(s, 1, 64);
      s += __shfl_xor(s, 2, 64);
      s += __shfl_xor(s, 4, 64);
      s += __shfl_xor(s, 8, 64);
      if (lane == 0) out[(q0 + qq) * ND + d] = s;
    }
  }
}

extern "C" void kernel_launch(void* const* d_in, const int* in_sizes, int n_in,
                              void* d_out, int out_size, void* d_ws, size_t ws_size,
                              hipStream_t stream) {
  const float* doc = (const float*)d_in[0];   // [128,128,128] fp32
  const float* qry = (const float*)d_in[1];   // [128,128,32]  fp32
  float* out = (float*)d_out;                 // [128,128]     fp32

  __hip_bfloat16* docB = (__hip_bfloat16*)d_ws;            // 4 MiB
  __hip_bfloat16* qB   = docB + ND * LD * EE;              // 1 MiB

  convert_kernel<<<dim3(2048 + NQ), dim3(256), 0, stream>>>(doc, qry, docB, qB);
  maxsim_kernel<<<dim3(ND / GDOCS, NQ / 8), dim3(256), 0, stream>>>(docB, qB, out);
}